// Round 1
// baseline (43.359 us; speedup 1.0000x reference)
//
#include <hip/hip_runtime.h>
#include <math.h>

#define LOG_2PI 1.8378770664093453f   // log(2*pi)
#define LOG_2   0.6931471805599453f   // log(2)

__device__ __forceinline__ float log_k1f(float x) {
    if (x <= 2.0f) {
        float t = x * (1.0f / 3.75f); t *= t;
        float i1 = x * (0.5f + t * (0.87890594f + t * (0.51498869f + t * (0.15084934f
                 + t * (0.02658733f + t * (0.00301532f + t * 0.00032411f))))));
        float u = 0.5f * x; u *= u;
        float ps = 1.0f + u * (0.15443144f + u * (-0.67278579f + u * (-0.18156897f
                 + u * (-0.01919402f + u * (-0.00110404f + u * (-0.00004686f))))));
        float k1s = logf(0.5f * x) * i1 + ps / x;
        return logf(k1s);
    } else {
        float v = 2.0f / x;
        float pl = 1.25331414f + v * (0.23498619f + v * (-0.03655620f + v * (0.01504268f
                 + v * (-0.00780353f + v * (0.00325614f - v * 0.00068245f)))));
        return -x - 0.5f * logf(x) + logf(pl);
    }
}

__global__ void zero_ws_kernel(double* ws) {
    if (threadIdx.x == 0 && blockIdx.x == 0) ws[0] = 0.0;
}

__global__ __launch_bounds__(256) void galnll_kernel(
        const float* __restrict__ m, const float* __restrict__ L,
        const float* __restrict__ x, double* __restrict__ ws, int B) {
    const float2* m2 = (const float2*)m;
    const float2* x2 = (const float2*)x;
    const float4* L4 = (const float4*)L;

    float local = 0.0f;
    int stride = gridDim.x * blockDim.x;
    for (int i = blockIdx.x * blockDim.x + threadIdx.x; i < B; i += stride) {
        float2 mv = m2[i];
        float2 xv = x2[i];
        float4 Lv = L4[i];           // [a, 0, c, b]
        float a = Lv.x, c = Lv.z, b = Lv.w;

        float S00 = a * a;
        float S01 = a * c;
        float S11 = c * c + b * b;
        float det = S00 * S11 - S01 * S01;    // = a^2 b^2
        float inv_det = 1.0f / det;

        // quadratic forms with Sinv = adj(S)/det
        float mSm = (mv.x * mv.x * S11 - 2.0f * mv.x * mv.y * S01 + mv.y * mv.y * S00) * inv_det;
        float xSx = (xv.x * xv.x * S11 - 2.0f * xv.x * xv.y * S01 + xv.y * xv.y * S00) * inv_det;
        float xSm = (xv.x * mv.x * S11 - (xv.x * mv.y + xv.y * mv.x) * S01 + xv.y * mv.y * S00) * inv_det;

        float ap = 2.0f + mSm;
        float z  = sqrtf(ap * xSx);

        float log_prob = LOG_2 + xSm - LOG_2PI
                       + 0.5f * logf(det)            // -0.5*logdet(Sinv) = +0.5*log(det)
                       + 0.5f * logf(xSx / ap)
                       + log_k1f(z);
        local += log_prob;
    }

    // wave-64 reduce in double
    double d = (double)local;
    for (int off = 32; off > 0; off >>= 1)
        d += __shfl_down(d, off, 64);

    __shared__ double wsum[4];
    int lane = threadIdx.x & 63;
    int wid  = threadIdx.x >> 6;
    if (lane == 0) wsum[wid] = d;
    __syncthreads();
    if (threadIdx.x == 0) {
        double s = wsum[0] + wsum[1] + wsum[2] + wsum[3];
        atomicAdd(ws, s);
    }
}

__global__ void finalize_kernel(const double* __restrict__ ws, float* __restrict__ out, int B) {
    if (threadIdx.x == 0 && blockIdx.x == 0)
        out[0] = (float)(-ws[0] / (double)B);
}

extern "C" void kernel_launch(void* const* d_in, const int* in_sizes, int n_in,
                              void* d_out, int out_size, void* d_ws, size_t ws_size,
                              hipStream_t stream) {
    const float* m = (const float*)d_in[0];
    const float* L = (const float*)d_in[1];
    const float* x = (const float*)d_in[2];
    float* out = (float*)d_out;
    double* ws = (double*)d_ws;

    int B = in_sizes[0] / 2;

    hipLaunchKernelGGL(zero_ws_kernel, dim3(1), dim3(64), 0, stream, ws);

    int block = 256;
    int grid = (B + block - 1) / block;
    if (grid > 2048) grid = 2048;
    hipLaunchKernelGGL(galnll_kernel, dim3(grid), dim3(block), 0, stream, m, L, x, ws, B);

    hipLaunchKernelGGL(finalize_kernel, dim3(1), dim3(64), 0, stream, ws, out, B);
}

// Round 2
// 21.070 us; speedup vs baseline: 2.0578x; 2.0578x over previous
//
#include <hip/hip_runtime.h>
#include <math.h>

#define LN2 0.6931471805599453f
#define C0  (-1.1447298858494002f)   // log(2) - log(2*pi)

__device__ __forceinline__ float flog2(float x) { return __builtin_amdgcn_logf(x); }
__device__ __forceinline__ float frcp(float x)  { return __builtin_amdgcn_rcpf(x); }

// log_prob for one row given m=(m0,m1), x=(x0,x1), L=[[a,0],[c,b]]
__device__ __forceinline__ float row_logprob(float m0, float m1, float x0, float x1,
                                             float a, float c, float b) {
    float ra = frcp(a), rb = frcp(b);
    // Cholesky solves: y = L^-1 m, w = L^-1 x
    float y0 = m0 * ra, y1 = (m1 - c * y0) * rb;
    float w0 = x0 * ra, w1 = (x1 - c * w0) * rb;
    float mSm = fmaf(y0, y0, y1 * y1);
    float xSx = fmaf(w0, w0, w1 * w1);
    float xSm = fmaf(w0, y0, w1 * y1);
    float ap = 2.0f + mSm;
    float z  = __builtin_amdgcn_sqrtf(ap * xSx);

    float l2ab = flog2(a) + flog2(b);       // 0.5*log2(det) = log2 a + log2 b
    float l2x  = flog2(xSx);
    float l2p  = flog2(ap);

    // ---- small branch (z <= 2), args clamped like the reference ----
    float zs = fminf(z, 2.0f);
    float t = zs * (1.0f / 3.75f); t *= t;
    float i1 = zs * fmaf(t, fmaf(t, fmaf(t, fmaf(t, fmaf(t, fmaf(t,
               0.00032411f, 0.00301532f), 0.02658733f), 0.15084934f),
               0.51498869f), 0.87890594f), 0.5f);
    float u = 0.5f * zs; u *= u;
    float ps = fmaf(u, fmaf(u, fmaf(u, fmaf(u, fmaf(u, fmaf(u,
               -0.00004686f, -0.00110404f), -0.01919402f), -0.18156897f),
               -0.67278579f), 0.15443144f), 1.0f);
    // ln(z/2) = ln2*(log2 z - 1), log2 z = 0.5*(l2p + l2x)
    float lnz_half = LN2 * fmaf(0.5f, l2p + l2x, -1.0f);
    float k1s = lnz_half * i1 + ps * frcp(zs);
    float lpS = LN2 * (l2ab + 0.5f * l2x - 0.5f * l2p + flog2(k1s));

    // ---- large branch (z > 2): -z - 0.5 ln z + ln(poly_l) merged ----
    float zl = fmaxf(z, 2.0f);
    float v = 2.0f * frcp(zl);
    float pl = fmaf(v, fmaf(v, fmaf(v, fmaf(v, fmaf(v, fmaf(v,
               -0.00068245f, 0.00325614f), -0.00780353f), 0.01504268f),
               -0.03655620f), 0.23498619f), 1.25331414f);
    float lpL = -z + LN2 * (l2ab + 0.25f * l2x - 0.75f * l2p + flog2(pl));

    float lp = (z <= 2.0f) ? lpS : lpL;
    return xSm + lp + C0;
}

__global__ __launch_bounds__(256) void galnll_kernel(
        const float* __restrict__ m, const float* __restrict__ L,
        const float* __restrict__ x, double* __restrict__ partials, int B) {
    const float4* m4 = (const float4*)m;
    const float4* x4 = (const float4*)x;
    const float4* L4 = (const float4*)L;

    int i = blockIdx.x * blockDim.x + threadIdx.x;   // pair index
    int base = 2 * i;
    float local = 0.0f;
    if (base + 1 < B) {
        float4 mv = m4[i];
        float4 xv = x4[i];
        float4 La = L4[base];
        float4 Lb = L4[base + 1];
        local = row_logprob(mv.x, mv.y, xv.x, xv.y, La.x, La.z, La.w)
              + row_logprob(mv.z, mv.w, xv.z, xv.w, Lb.x, Lb.z, Lb.w);
    } else if (base < B) {  // odd tail
        const float2* m2 = (const float2*)m;
        const float2* x2 = (const float2*)x;
        float2 mv = m2[base];
        float2 xv = x2[base];
        float4 La = L4[base];
        local = row_logprob(mv.x, mv.y, xv.x, xv.y, La.x, La.z, La.w);
    }

    double d = (double)local;
    for (int off = 32; off > 0; off >>= 1)
        d += __shfl_down(d, off, 64);

    __shared__ double wsum[4];
    int lane = threadIdx.x & 63;
    int wid  = threadIdx.x >> 6;
    if (lane == 0) wsum[wid] = d;
    __syncthreads();
    if (threadIdx.x == 0)
        partials[blockIdx.x] = wsum[0] + wsum[1] + wsum[2] + wsum[3];
}

__global__ __launch_bounds__(256) void reduce_kernel(
        const double* __restrict__ partials, int n, float* __restrict__ out, int B) {
    double d = 0.0;
    for (int i = threadIdx.x; i < n; i += 256)
        d += partials[i];
    for (int off = 32; off > 0; off >>= 1)
        d += __shfl_down(d, off, 64);
    __shared__ double wsum[4];
    int lane = threadIdx.x & 63;
    int wid  = threadIdx.x >> 6;
    if (lane == 0) wsum[wid] = d;
    __syncthreads();
    if (threadIdx.x == 0) {
        double s = wsum[0] + wsum[1] + wsum[2] + wsum[3];
        out[0] = (float)(-s / (double)B);
    }
}

extern "C" void kernel_launch(void* const* d_in, const int* in_sizes, int n_in,
                              void* d_out, int out_size, void* d_ws, size_t ws_size,
                              hipStream_t stream) {
    const float* m = (const float*)d_in[0];
    const float* L = (const float*)d_in[1];
    const float* x = (const float*)d_in[2];
    float* out = (float*)d_out;
    double* partials = (double*)d_ws;

    int B = in_sizes[0] / 2;
    int npairs = (B + 1) / 2;
    int block = 256;
    int grid = (npairs + block - 1) / block;

    hipLaunchKernelGGL(galnll_kernel, dim3(grid), dim3(block), 0, stream,
                       m, L, x, partials, B);
    hipLaunchKernelGGL(reduce_kernel, dim3(1), dim3(block), 0, stream,
                       partials, grid, out, B);
}

// Round 3
// 19.527 us; speedup vs baseline: 2.2205x; 1.0790x over previous
//
#include <hip/hip_runtime.h>
#include <math.h>

#define LN2 0.6931471805599453f
#define C0  (-1.1447298858494002f)   // log(2) - log(2*pi)

__device__ __forceinline__ float flog2(float x) { return __builtin_amdgcn_logf(x); }
__device__ __forceinline__ float frcp(float x)  { return __builtin_amdgcn_rcpf(x); }

// log_prob for one row given m=(m0,m1), x=(x0,x1), L=[[a,0],[c,b]]
__device__ __forceinline__ float row_logprob(float m0, float m1, float x0, float x1,
                                             float a, float c, float b) {
    float ra = frcp(a), rb = frcp(b);
    // Cholesky solves: y = L^-1 m, w = L^-1 x
    float y0 = m0 * ra, y1 = (m1 - c * y0) * rb;
    float w0 = x0 * ra, w1 = (x1 - c * w0) * rb;
    float mSm = fmaf(y0, y0, y1 * y1);
    float xSx = fmaf(w0, w0, w1 * w1);
    float xSm = fmaf(w0, y0, w1 * y1);
    float ap = 2.0f + mSm;
    float z  = __builtin_amdgcn_sqrtf(ap * xSx);

    float l2ab = flog2(a) + flog2(b);       // 0.5*log2(det) = log2 a + log2 b
    float l2x  = flog2(xSx);
    float l2p  = flog2(ap);

    // ---- small branch (z <= 2), args clamped like the reference ----
    float zs = fminf(z, 2.0f);
    float t = zs * (1.0f / 3.75f); t *= t;
    float i1 = zs * fmaf(t, fmaf(t, fmaf(t, fmaf(t, fmaf(t, fmaf(t,
               0.00032411f, 0.00301532f), 0.02658733f), 0.15084934f),
               0.51498869f), 0.87890594f), 0.5f);
    float u = 0.5f * zs; u *= u;
    float ps = fmaf(u, fmaf(u, fmaf(u, fmaf(u, fmaf(u, fmaf(u,
               -0.00004686f, -0.00110404f), -0.01919402f), -0.18156897f),
               -0.67278579f), 0.15443144f), 1.0f);
    // ln(z/2) = ln2*(log2 z - 1), log2 z = 0.5*(l2p + l2x)
    float lnz_half = LN2 * fmaf(0.5f, l2p + l2x, -1.0f);
    float k1s = lnz_half * i1 + ps * frcp(zs);
    float lpS = LN2 * (l2ab + 0.5f * l2x - 0.5f * l2p + flog2(k1s));

    // ---- large branch (z > 2): -z - 0.5 ln z + ln(poly_l) merged ----
    float zl = fmaxf(z, 2.0f);
    float v = 2.0f * frcp(zl);
    float pl = fmaf(v, fmaf(v, fmaf(v, fmaf(v, fmaf(v, fmaf(v,
               -0.00068245f, 0.00325614f), -0.00780353f), 0.01504268f),
               -0.03655620f), 0.23498619f), 1.25331414f);
    float lpL = -z + LN2 * (l2ab + 0.25f * l2x - 0.75f * l2p + flog2(pl));

    float lp = (z <= 2.0f) ? lpS : lpL;
    return xSm + lp + C0;
}

// 4 rows per thread: 2x float4 of m, 2x float4 of x, 4x float4 of L (128 B/thread)
__global__ __launch_bounds__(256) void galnll_kernel(
        const float* __restrict__ m, const float* __restrict__ L,
        const float* __restrict__ x, double* __restrict__ partials, int B) {
    const float4* m4 = (const float4*)m;
    const float4* x4 = (const float4*)x;
    const float4* L4 = (const float4*)L;

    int t = blockIdx.x * blockDim.x + threadIdx.x;   // quad index
    int r = 4 * t;                                   // first row of this thread
    float local = 0.0f;
    if (r + 3 < B) {
        // issue all 8 loads up front for MLP
        float4 mA = m4[2 * t];
        float4 mB = m4[2 * t + 1];
        float4 xA = x4[2 * t];
        float4 xB = x4[2 * t + 1];
        float4 L0 = L4[r];
        float4 L1 = L4[r + 1];
        float4 L2 = L4[r + 2];
        float4 L3 = L4[r + 3];
        local = row_logprob(mA.x, mA.y, xA.x, xA.y, L0.x, L0.z, L0.w)
              + row_logprob(mA.z, mA.w, xA.z, xA.w, L1.x, L1.z, L1.w)
              + row_logprob(mB.x, mB.y, xB.x, xB.y, L2.x, L2.z, L2.w)
              + row_logprob(mB.z, mB.w, xB.z, xB.w, L3.x, L3.z, L3.w);
    } else {
        const float2* m2 = (const float2*)m;
        const float2* x2 = (const float2*)x;
        for (int i = r; i < B; ++i) {
            float2 mv = m2[i];
            float2 xv = x2[i];
            float4 Lv = L4[i];
            local += row_logprob(mv.x, mv.y, xv.x, xv.y, Lv.x, Lv.z, Lv.w);
        }
    }

    double d = (double)local;
    for (int off = 32; off > 0; off >>= 1)
        d += __shfl_down(d, off, 64);

    __shared__ double wsum[4];
    int lane = threadIdx.x & 63;
    int wid  = threadIdx.x >> 6;
    if (lane == 0) wsum[wid] = d;
    __syncthreads();
    if (threadIdx.x == 0)
        partials[blockIdx.x] = wsum[0] + wsum[1] + wsum[2] + wsum[3];
}

__global__ __launch_bounds__(256) void reduce_kernel(
        const double* __restrict__ partials, int n, float* __restrict__ out, int B) {
    double d = 0.0;
    for (int i = threadIdx.x; i < n; i += 256)
        d += partials[i];
    for (int off = 32; off > 0; off >>= 1)
        d += __shfl_down(d, off, 64);
    __shared__ double wsum[4];
    int lane = threadIdx.x & 63;
    int wid  = threadIdx.x >> 6;
    if (lane == 0) wsum[wid] = d;
    __syncthreads();
    if (threadIdx.x == 0) {
        double s = wsum[0] + wsum[1] + wsum[2] + wsum[3];
        out[0] = (float)(-s / (double)B);
    }
}

extern "C" void kernel_launch(void* const* d_in, const int* in_sizes, int n_in,
                              void* d_out, int out_size, void* d_ws, size_t ws_size,
                              hipStream_t stream) {
    const float* m = (const float*)d_in[0];
    const float* L = (const float*)d_in[1];
    const float* x = (const float*)d_in[2];
    float* out = (float*)d_out;
    double* partials = (double*)d_ws;

    int B = in_sizes[0] / 2;
    int nquads = (B + 3) / 4;
    int block = 256;
    int grid = (nquads + block - 1) / block;

    hipLaunchKernelGGL(galnll_kernel, dim3(grid), dim3(block), 0, stream,
                       m, L, x, partials, B);
    hipLaunchKernelGGL(reduce_kernel, dim3(1), dim3(block), 0, stream,
                       partials, grid, out, B);
}